// Round 1
// baseline (415.518 us; speedup 1.0000x reference)
//
#include <hip/hip_runtime.h>

typedef __bf16 bf16;
typedef __bf16 bf16x8 __attribute__((ext_vector_type(8)));
typedef float f32x4 __attribute__((ext_vector_type(4)));

#define DIM 768
#define HEADS 12
#define HD 64
#define HIDDEN 1536
#define BB 8
#define NN 1024
#define ROWS (BB*NN)

__device__ __forceinline__ void gload_lds16(const void* g, void* l) {
  __builtin_amdgcn_global_load_lds(
      (const __attribute__((address_space(1))) void*)g,
      (__attribute__((address_space(3))) void*)l, 16, 0, 0);
}

// ---------------- LayerNorm (fp32 in -> bf16 out) ----------------
__global__ __launch_bounds__(256) void ln_kernel(
    const float* __restrict__ x, const float* __restrict__ gw,
    const float* __restrict__ bw, bf16* __restrict__ out)
{
  const int row = blockIdx.x;
  const int tid = threadIdx.x;
  const float* xr = x + (size_t)row * DIM;
  float v0 = xr[tid], v1 = xr[tid + 256], v2 = xr[tid + 512];
  float s1 = v0 + v1 + v2;
  float s2 = v0*v0 + v1*v1 + v2*v2;
#pragma unroll
  for (int off = 1; off < 64; off <<= 1) {
    s1 += __shfl_xor(s1, off);
    s2 += __shfl_xor(s2, off);
  }
  __shared__ float red[8];
  const int w = tid >> 6, lane = tid & 63;
  if (lane == 0) { red[w] = s1; red[4 + w] = s2; }
  __syncthreads();
  s1 = red[0] + red[1] + red[2] + red[3];
  s2 = red[4] + red[5] + red[6] + red[7];
  const float mu = s1 * (1.f / DIM);
  const float rstd = rsqrtf(s2 * (1.f / DIM) - mu * mu + 1e-5f);
  bf16* orow = out + (size_t)row * DIM;
  orow[tid]       = (bf16)((v0 - mu) * rstd * gw[tid]       + bw[tid]);
  orow[tid + 256] = (bf16)((v1 - mu) * rstd * gw[tid + 256] + bw[tid + 256]);
  orow[tid + 512] = (bf16)((v2 - mu) * rstd * gw[tid + 512] + bw[tid + 512]);
}

// ------------- weight transpose + f32->bf16: in[K][N] -> out[N][K] -------------
__global__ void wtrans_kernel(const float* __restrict__ in, bf16* __restrict__ out,
                              int K, int N)
{
  __shared__ float t[32][33];
  const int tx = threadIdx.x, ty = threadIdx.y;
  const int n0 = blockIdx.x * 32, k0 = blockIdx.y * 32;
#pragma unroll
  for (int i = 0; i < 32; i += 8)
    t[ty + i][tx] = in[(size_t)(k0 + ty + i) * N + n0 + tx];
  __syncthreads();
#pragma unroll
  for (int i = 0; i < 32; i += 8)
    out[(size_t)(n0 + ty + i) * K + k0 + tx] = (bf16)t[tx][ty + i];
}

// ---------------- GEMM: C[M][N] = A[M][K] * Bt[N][K]^T, m97-style ----------------
// EPI 0: QKV split -> Qb (x0.125) / Kb / Vtb (transposed)
// EPI 1: +bias +resid -> f32 out
// EPI 2: +bias, exact GELU -> bf16 out
// EPI 3: +bias +resid -> f32 out (same as 1)
template<int EPI>
__global__ __launch_bounds__(256, 2) void gemm128(
    const bf16* __restrict__ A, const bf16* __restrict__ Bt,
    int M, int N, int K,
    const float* __restrict__ bias, const float* __restrict__ resid,
    void* __restrict__ o0, void* __restrict__ o1, void* __restrict__ o2)
{
  __shared__ bf16 sA[128 * 64];
  __shared__ bf16 sB[128 * 64];
  const int tid = threadIdx.x;
  const int lane = tid & 63, w = tid >> 6;
  const int wrow = w >> 1, wcol = w & 1;
  const int m0 = blockIdx.y * 128, n0 = blockIdx.x * 128;
  const int l15 = lane & 15, l4 = lane >> 4;

  f32x4 acc[4][4] = {};

  const int crow = lane >> 3;
  const int cbyte = (lane & 7) * 16;
  const int ksteps = K >> 6;
  for (int kt = 0; kt < ksteps; ++kt) {
    const int k0 = kt << 6;
    __syncthreads();
#pragma unroll
    for (int c2 = 0; c2 < 4; ++c2) {
      const int c = (w << 2) + c2;
      const int r = (c << 3) + crow;
      gload_lds16((const char*)(A + (size_t)(m0 + r) * K + k0) + cbyte,
                  (char*)sA + c * 1024);
      gload_lds16((const char*)(Bt + (size_t)(n0 + r) * K + k0) + cbyte,
                  (char*)sB + c * 1024);
    }
    __syncthreads();
#pragma unroll
    for (int kk = 0; kk < 64; kk += 32) {
      bf16x8 af[4], bfv[4];
#pragma unroll
      for (int mf = 0; mf < 4; ++mf)
        af[mf] = *(const bf16x8*)(sA + (wrow * 64 + mf * 16 + l15) * 64 + kk + l4 * 8);
#pragma unroll
      for (int nf = 0; nf < 4; ++nf)
        bfv[nf] = *(const bf16x8*)(sB + (wcol * 64 + nf * 16 + l15) * 64 + kk + l4 * 8);
#pragma unroll
      for (int mf = 0; mf < 4; ++mf)
#pragma unroll
        for (int nf = 0; nf < 4; ++nf)
          acc[mf][nf] = __builtin_amdgcn_mfma_f32_16x16x32_bf16(af[mf], bfv[nf], acc[mf][nf], 0, 0, 0);
    }
  }

#pragma unroll
  for (int mf = 0; mf < 4; ++mf) {
    const int rbase = m0 + wrow * 64 + mf * 16 + l4 * 4;
#pragma unroll
    for (int nf = 0; nf < 4; ++nf) {
      const int colbase = n0 + wcol * 64 + nf * 16;
      const int col = colbase + l15;
      if constexpr (EPI == 0) {
        const int seg = colbase / 768;
        const int hh_ = (colbase - seg * 768) >> 6;
        const int dd = (colbase & 63) + l15;
        const int b_ = rbase >> 10;
        const int ns = rbase & 1023;
        const size_t gh = (size_t)(b_ * HEADS + hh_);
        bf16* Qb = (bf16*)o0; bf16* Kb = (bf16*)o1; bf16* Vtb = (bf16*)o2;
        if (seg == 0) {
#pragma unroll
          for (int rg = 0; rg < 4; ++rg)
            Qb[(gh * NN + ns + rg) * HD + dd] = (bf16)(acc[mf][nf][rg] * 0.125f);
        } else if (seg == 1) {
#pragma unroll
          for (int rg = 0; rg < 4; ++rg)
            Kb[(gh * NN + ns + rg) * HD + dd] = (bf16)acc[mf][nf][rg];
        } else {
          union { ushort4 u4; unsigned short us[4]; } pk;
#pragma unroll
          for (int rg = 0; rg < 4; ++rg)
            pk.us[rg] = __builtin_bit_cast(unsigned short, (bf16)acc[mf][nf][rg]);
          *(ushort4*)(Vtb + (gh * HD + dd) * NN + ns) = pk.u4;
        }
      } else if constexpr (EPI == 1 || EPI == 3) {
        float* outp = (float*)o0;
#pragma unroll
        for (int rg = 0; rg < 4; ++rg) {
          const size_t idx = (size_t)(rbase + rg) * N + col;
          outp[idx] = acc[mf][nf][rg] + bias[col] + resid[idx];
        }
      } else {
        bf16* outp = (bf16*)o0;
#pragma unroll
        for (int rg = 0; rg < 4; ++rg) {
          float v = acc[mf][nf][rg] + bias[col];
          float gl = 0.5f * v * (1.0f + erff(v * 0.70710678118654752f));
          outp[(size_t)(rbase + rg) * N + col] = (bf16)gl;
        }
      }
    }
  }
}

// ---------------- flash attention with rpe bias ----------------
// Qb/Kb: [96][1024][64] bf16 (Q pre-scaled by 0.125); Vtb: [96][64][1024] bf16
__global__ __launch_bounds__(256, 2) void attn_kernel(
    const bf16* __restrict__ Qb, const bf16* __restrict__ Kb,
    const bf16* __restrict__ Vtb, const float* __restrict__ rpe,
    bf16* __restrict__ o_attn)
{
  __shared__ bf16 sK[64 * 64];   // [kv][d], XOR-swizzled rows
  __shared__ bf16 sV[64 * 64];   // [d][kv], XOR-swizzled rows
  __shared__ bf16 sP[4 * 16 * 64]; // per-wave P, XOR-swizzled rows
  const int tid = threadIdx.x;
  const int lane = tid & 63, w = tid >> 6;
  const int l15 = lane & 15, l4 = lane >> 4;
  const int bid = blockIdx.x;
  const int g = bid >> 4, qt = bid & 15;
  const int b_ = g / HEADS, h_ = g % HEADS;
  const int qbase = qt * 64 + w * 16;

  bf16x8 qf[2];
  {
    const bf16* qp = Qb + ((size_t)g * NN + qbase + l15) * HD + l4 * 8;
    qf[0] = *(const bf16x8*)qp;
    qf[1] = *(const bf16x8*)(qp + 32);
  }

  f32x4 oacc[4] = {};
  float m_r[4] = {-1e30f, -1e30f, -1e30f, -1e30f};
  float l_r[4] = {};
  const float* rpe_h = rpe + (size_t)h_ * NN * NN;

  const int crow = lane >> 3;
  const int scol = ((lane & 7) * 16) ^ ((crow & 7) << 4); // pre-swizzled source col

  for (int kv0 = 0; kv0 < NN; kv0 += 64) {
    __syncthreads();
#pragma unroll
    for (int c2 = 0; c2 < 2; ++c2) {
      const int c = w * 2 + c2;
      const int r = c * 8 + crow;
      gload_lds16((const char*)(Kb + ((size_t)g * NN + kv0) * HD) + r * 128 + scol,
                  (char*)sK + c * 1024);
      gload_lds16((const char*)(Vtb + ((size_t)g * HD + r) * NN + kv0) + scol,
                  (char*)sV + c * 1024);
    }
    __syncthreads();

    // S = Q K^T (scale folded into Q)
    f32x4 s[4] = {};
#pragma unroll
    for (int kh = 0; kh < 2; ++kh) {
#pragma unroll
      for (int nf = 0; nf < 4; ++nf) {
        const int n_ = nf * 16 + l15;
        const bf16x8 kf = *(const bf16x8*)((const char*)sK + n_ * 128 +
                            (((kh * 32 + l4 * 8) * 2) ^ ((n_ & 7) << 4)));
        s[nf] = __builtin_amdgcn_mfma_f32_16x16x32_bf16(qf[kh], kf, s[nf], 0, 0, 0);
      }
    }
    // + rpe bias, row max
    float rm[4] = {-1e30f, -1e30f, -1e30f, -1e30f};
#pragma unroll
    for (int nf = 0; nf < 4; ++nf) {
      const int kvc = kv0 + nf * 16 + l15;
#pragma unroll
      for (int rg = 0; rg < 4; ++rg) {
        const int qr = qbase + l4 * 4 + rg;
        float v = s[nf][rg] + rpe_h[(size_t)qr * NN + kvc];
        s[nf][rg] = v;
        rm[rg] = fmaxf(rm[rg], v);
      }
    }
#pragma unroll
    for (int off = 1; off <= 8; off <<= 1)
#pragma unroll
      for (int rg = 0; rg < 4; ++rg)
        rm[rg] = fmaxf(rm[rg], __shfl_xor(rm[rg], off));
    float al[4];
#pragma unroll
    for (int rg = 0; rg < 4; ++rg) {
      const float mn = fmaxf(m_r[rg], rm[rg]);
      al[rg] = __expf(m_r[rg] - mn);
      m_r[rg] = mn;
    }
    float rs[4] = {};
#pragma unroll
    for (int nf = 0; nf < 4; ++nf)
#pragma unroll
      for (int rg = 0; rg < 4; ++rg) {
        const float p = __expf(s[nf][rg] - m_r[rg]);
        rs[rg] += p;
        const int r = l4 * 4 + rg;
        const int cb = (nf * 16 + l15) * 2;
        *(bf16*)((char*)sP + w * 2048 + r * 128 + (cb ^ ((r & 7) << 4))) = (bf16)p;
      }
#pragma unroll
    for (int off = 1; off <= 8; off <<= 1)
#pragma unroll
      for (int rg = 0; rg < 4; ++rg)
        rs[rg] += __shfl_xor(rs[rg], off);
#pragma unroll
    for (int rg = 0; rg < 4; ++rg)
      l_r[rg] = l_r[rg] * al[rg] + rs[rg];
#pragma unroll
    for (int df = 0; df < 4; ++df)
#pragma unroll
      for (int rg = 0; rg < 4; ++rg)
        oacc[df][rg] *= al[rg];
    __syncthreads(); // sP writes drained (lgkmcnt) before PV reads

    // O += P V
#pragma unroll
    for (int kh = 0; kh < 2; ++kh) {
      const bf16x8 pf = *(const bf16x8*)((const char*)sP + w * 2048 + l15 * 128 +
                          (((kh * 32 + l4 * 8) * 2) ^ ((l15 & 7) << 4)));
#pragma unroll
      for (int df = 0; df < 4; ++df) {
        const int d_ = df * 16 + l15;
        const bf16x8 vf = *(const bf16x8*)((const char*)sV + d_ * 128 +
                            (((kh * 32 + l4 * 8) * 2) ^ ((d_ & 7) << 4)));
        oacc[df] = __builtin_amdgcn_mfma_f32_16x16x32_bf16(pf, vf, oacc[df], 0, 0, 0);
      }
    }
  }

#pragma unroll
  for (int rg = 0; rg < 4; ++rg) {
    const float inv = 1.0f / l_r[rg];
    const int qr = qbase + l4 * 4 + rg;
    bf16* orow = o_attn + ((size_t)(b_ * NN) + qr) * DIM + h_ * HD;
#pragma unroll
    for (int df = 0; df < 4; ++df)
      orow[df * 16 + l15] = (bf16)(oacc[df][rg] * inv);
  }
}

extern "C" void kernel_launch(void* const* d_in, const int* in_sizes, int n_in,
                              void* d_out, int out_size, void* d_ws, size_t ws_size,
                              hipStream_t stream)
{
  const float* x      = (const float*)d_in[0];
  const float* rpe    = (const float*)d_in[1];
  const float* qkv_w  = (const float*)d_in[2];
  const float* proj_w = (const float*)d_in[3];
  const float* proj_b = (const float*)d_in[4];
  const float* ln1_g  = (const float*)d_in[5];
  const float* ln1_b  = (const float*)d_in[6];
  const float* ln2_g  = (const float*)d_in[7];
  const float* ln2_b  = (const float*)d_in[8];
  const float* fc1_w  = (const float*)d_in[9];
  const float* fc1_b  = (const float*)d_in[10];
  const float* fc2_w  = (const float*)d_in[11];
  const float* fc2_b  = (const float*)d_in[12];
  float* out = (float*)d_out;

  char* ws = (char*)d_ws;
  size_t off = 0;
  bf16* qkv_wT  = (bf16*)(ws + off); off += (size_t)2304 * 768 * 2;
  bf16* proj_wT = (bf16*)(ws + off); off += (size_t)768 * 768 * 2;
  bf16* fc1_wT  = (bf16*)(ws + off); off += (size_t)1536 * 768 * 2;
  bf16* fc2_wT  = (bf16*)(ws + off); off += (size_t)768 * 1536 * 2;
  bf16* hbuf    = (bf16*)(ws + off); off += (size_t)ROWS * DIM * 2;   // ln1 out, then o_attn
  bf16* Qb      = (bf16*)(ws + off); off += (size_t)96 * NN * HD * 2; // then h2
  bf16* Kb      = (bf16*)(ws + off); off += (size_t)96 * NN * HD * 2; // then fc1-out (with Vtb)
  bf16* Vtb     = (bf16*)(ws + off); off += (size_t)96 * HD * NN * 2;
  float* x1     = (float*)(ws + off); off += (size_t)ROWS * DIM * 4;
  bf16* o_attn = hbuf;
  bf16* h2 = Qb;
  bf16* hh = Kb;

  dim3 tb(32, 8);
  wtrans_kernel<<<dim3(2304 / 32, 768 / 32), tb, 0, stream>>>(qkv_w, qkv_wT, 768, 2304);
  wtrans_kernel<<<dim3(768 / 32, 768 / 32),  tb, 0, stream>>>(proj_w, proj_wT, 768, 768);
  wtrans_kernel<<<dim3(1536 / 32, 768 / 32), tb, 0, stream>>>(fc1_w, fc1_wT, 768, 1536);
  wtrans_kernel<<<dim3(768 / 32, 1536 / 32), tb, 0, stream>>>(fc2_w, fc2_wT, 1536, 768);

  ln_kernel<<<ROWS, 256, 0, stream>>>(x, ln1_g, ln1_b, hbuf);
  gemm128<0><<<dim3(2304 / 128, ROWS / 128), 256, 0, stream>>>(
      hbuf, qkv_wT, ROWS, 2304, 768, nullptr, nullptr, (void*)Qb, (void*)Kb, (void*)Vtb);
  attn_kernel<<<96 * 16, 256, 0, stream>>>(Qb, Kb, Vtb, rpe, o_attn);
  gemm128<1><<<dim3(768 / 128, ROWS / 128), 256, 0, stream>>>(
      o_attn, proj_wT, ROWS, 768, 768, proj_b, x, (void*)x1, nullptr, nullptr);
  ln_kernel<<<ROWS, 256, 0, stream>>>(x1, ln2_g, ln2_b, h2);
  gemm128<2><<<dim3(1536 / 128, ROWS / 128), 256, 0, stream>>>(
      h2, fc1_wT, ROWS, 1536, 768, fc1_b, nullptr, (void*)hh, nullptr, nullptr);
  gemm128<3><<<dim3(768 / 128, ROWS / 128), 256, 0, stream>>>(
      hh, fc2_wT, ROWS, 768, 1536, fc2_b, x1, (void*)out, nullptr, nullptr);
}

// Round 2
// 399.286 us; speedup vs baseline: 1.0407x; 1.0407x over previous
//
#include <hip/hip_runtime.h>

typedef __bf16 bf16;
typedef __bf16 bf16x8 __attribute__((ext_vector_type(8)));
typedef float f32x4 __attribute__((ext_vector_type(4)));

#define DIM 768
#define HEADS 12
#define HD 64
#define HIDDEN 1536
#define BB 8
#define NN 1024
#define ROWS (BB*NN)

__device__ __forceinline__ void gload_lds16(const void* g, void* l) {
  __builtin_amdgcn_global_load_lds(
      (const __attribute__((address_space(1))) void*)g,
      (__attribute__((address_space(3))) void*)l, 16, 0, 0);
}

// ---------------- rpe f32 -> bf16 ----------------
__global__ __launch_bounds__(256) void rpe_cvt_kernel(
    const float* __restrict__ in, bf16* __restrict__ out)
{
  const size_t total = (size_t)HEADS * NN * NN;
  const size_t stride = (size_t)gridDim.x * 256 * 4;
  for (size_t i = ((size_t)blockIdx.x * 256 + threadIdx.x) * 4; i < total; i += stride) {
    const float4 v = *(const float4*)(in + i);
    ushort4 u;
    u.x = __builtin_bit_cast(unsigned short, (bf16)v.x);
    u.y = __builtin_bit_cast(unsigned short, (bf16)v.y);
    u.z = __builtin_bit_cast(unsigned short, (bf16)v.z);
    u.w = __builtin_bit_cast(unsigned short, (bf16)v.w);
    *(ushort4*)(out + i) = u;
  }
}

// ---------------- LayerNorm (fp32 in -> bf16 out) ----------------
__global__ __launch_bounds__(256) void ln_kernel(
    const float* __restrict__ x, const float* __restrict__ gw,
    const float* __restrict__ bw, bf16* __restrict__ out)
{
  const int row = blockIdx.x;
  const int tid = threadIdx.x;
  const float* xr = x + (size_t)row * DIM;
  float v0 = xr[tid], v1 = xr[tid + 256], v2 = xr[tid + 512];
  float s1 = v0 + v1 + v2;
  float s2 = v0*v0 + v1*v1 + v2*v2;
#pragma unroll
  for (int off = 1; off < 64; off <<= 1) {
    s1 += __shfl_xor(s1, off);
    s2 += __shfl_xor(s2, off);
  }
  __shared__ float red[8];
  const int w = tid >> 6, lane = tid & 63;
  if (lane == 0) { red[w] = s1; red[4 + w] = s2; }
  __syncthreads();
  s1 = red[0] + red[1] + red[2] + red[3];
  s2 = red[4] + red[5] + red[6] + red[7];
  const float mu = s1 * (1.f / DIM);
  const float rstd = rsqrtf(s2 * (1.f / DIM) - mu * mu + 1e-5f);
  bf16* orow = out + (size_t)row * DIM;
  orow[tid]       = (bf16)((v0 - mu) * rstd * gw[tid]       + bw[tid]);
  orow[tid + 256] = (bf16)((v1 - mu) * rstd * gw[tid + 256] + bw[tid + 256]);
  orow[tid + 512] = (bf16)((v2 - mu) * rstd * gw[tid + 512] + bw[tid + 512]);
}

// ------------- weight transpose + f32->bf16: in[K][N] -> out[N][K] -------------
__global__ void wtrans_kernel(const float* __restrict__ in, bf16* __restrict__ out,
                              int K, int N)
{
  __shared__ float t[32][33];
  const int tx = threadIdx.x, ty = threadIdx.y;
  const int n0 = blockIdx.x * 32, k0 = blockIdx.y * 32;
#pragma unroll
  for (int i = 0; i < 32; i += 8)
    t[ty + i][tx] = in[(size_t)(k0 + ty + i) * N + n0 + tx];
  __syncthreads();
#pragma unroll
  for (int i = 0; i < 32; i += 8)
    out[(size_t)(n0 + ty + i) * K + k0 + tx] = (bf16)t[tx][ty + i];
}

// ---------------- GEMM: C[M][N] = A[M][K] * Bt[N][K]^T, m97-style ----------------
template<int EPI>
__global__ __launch_bounds__(256, 2) void gemm128(
    const bf16* __restrict__ A, const bf16* __restrict__ Bt,
    int M, int N, int K,
    const float* __restrict__ bias, const float* __restrict__ resid,
    void* __restrict__ o0, void* __restrict__ o1, void* __restrict__ o2)
{
  __shared__ bf16 sA[128 * 64];
  __shared__ bf16 sB[128 * 64];
  const int tid = threadIdx.x;
  const int lane = tid & 63, w = tid >> 6;
  const int wrow = w >> 1, wcol = w & 1;
  const int m0 = blockIdx.y * 128, n0 = blockIdx.x * 128;
  const int l15 = lane & 15, l4 = lane >> 4;

  f32x4 acc[4][4] = {};

  const int crow = lane >> 3;
  const int cbyte = (lane & 7) * 16;
  const int ksteps = K >> 6;
  for (int kt = 0; kt < ksteps; ++kt) {
    const int k0 = kt << 6;
    __syncthreads();
#pragma unroll
    for (int c2 = 0; c2 < 4; ++c2) {
      const int c = (w << 2) + c2;
      const int r = (c << 3) + crow;
      gload_lds16((const char*)(A + (size_t)(m0 + r) * K + k0) + cbyte,
                  (char*)sA + c * 1024);
      gload_lds16((const char*)(Bt + (size_t)(n0 + r) * K + k0) + cbyte,
                  (char*)sB + c * 1024);
    }
    __syncthreads();
#pragma unroll
    for (int kk = 0; kk < 64; kk += 32) {
      bf16x8 af[4], bfv[4];
#pragma unroll
      for (int mf = 0; mf < 4; ++mf)
        af[mf] = *(const bf16x8*)(sA + (wrow * 64 + mf * 16 + l15) * 64 + kk + l4 * 8);
#pragma unroll
      for (int nf = 0; nf < 4; ++nf)
        bfv[nf] = *(const bf16x8*)(sB + (wcol * 64 + nf * 16 + l15) * 64 + kk + l4 * 8);
#pragma unroll
      for (int mf = 0; mf < 4; ++mf)
#pragma unroll
        for (int nf = 0; nf < 4; ++nf)
          acc[mf][nf] = __builtin_amdgcn_mfma_f32_16x16x32_bf16(af[mf], bfv[nf], acc[mf][nf], 0, 0, 0);
    }
  }

#pragma unroll
  for (int mf = 0; mf < 4; ++mf) {
    const int rbase = m0 + wrow * 64 + mf * 16 + l4 * 4;
#pragma unroll
    for (int nf = 0; nf < 4; ++nf) {
      const int colbase = n0 + wcol * 64 + nf * 16;
      const int col = colbase + l15;
      if constexpr (EPI == 0) {
        const int seg = colbase / 768;
        const int hh_ = (colbase - seg * 768) >> 6;
        const int dd = (colbase & 63) + l15;
        const int b_ = rbase >> 10;
        const int ns = rbase & 1023;
        const size_t gh = (size_t)(b_ * HEADS + hh_);
        bf16* Qb = (bf16*)o0; bf16* Kb = (bf16*)o1; bf16* Vtb = (bf16*)o2;
        if (seg == 0) {
#pragma unroll
          for (int rg = 0; rg < 4; ++rg)
            Qb[(gh * NN + ns + rg) * HD + dd] = (bf16)(acc[mf][nf][rg] * 0.125f);
        } else if (seg == 1) {
#pragma unroll
          for (int rg = 0; rg < 4; ++rg)
            Kb[(gh * NN + ns + rg) * HD + dd] = (bf16)acc[mf][nf][rg];
        } else {
          union { ushort4 u4; unsigned short us[4]; } pk;
#pragma unroll
          for (int rg = 0; rg < 4; ++rg)
            pk.us[rg] = __builtin_bit_cast(unsigned short, (bf16)acc[mf][nf][rg]);
          *(ushort4*)(Vtb + (gh * HD + dd) * NN + ns) = pk.u4;
        }
      } else if constexpr (EPI == 1 || EPI == 3) {
        float* outp = (float*)o0;
#pragma unroll
        for (int rg = 0; rg < 4; ++rg) {
          const size_t idx = (size_t)(rbase + rg) * N + col;
          outp[idx] = acc[mf][nf][rg] + bias[col] + resid[idx];
        }
      } else {
        bf16* outp = (bf16*)o0;
#pragma unroll
        for (int rg = 0; rg < 4; ++rg) {
          float v = acc[mf][nf][rg] + bias[col];
          float gl = 0.5f * v * (1.0f + erff(v * 0.70710678118654752f));
          outp[(size_t)(rbase + rg) * N + col] = (bf16)gl;
        }
      }
    }
  }
}

// ---------------- flash attention with bf16 rpe bias, 2-phase pipelined ----------------
// Qb/Kb: [96][1024][64] bf16 (Q pre-scaled); Vtb: [96][64][1024] bf16; rpeb: [12][1024][1024] bf16
__global__ __launch_bounds__(256, 4) void attn_kernel(
    const bf16* __restrict__ Qb, const bf16* __restrict__ Kb,
    const bf16* __restrict__ Vtb, const bf16* __restrict__ rpeb,
    bf16* __restrict__ o_attn)
{
  __shared__ bf16 sK[2][64 * 64];   // [kv][d], XOR-swizzled rows
  __shared__ bf16 sV[2][64 * 64];   // [d][kv], XOR-swizzled rows
  __shared__ bf16 sP[4 * 16 * 64];  // per-wave P, XOR-swizzled rows
  const int tid = threadIdx.x;
  const int lane = tid & 63, w = tid >> 6;
  const int l15 = lane & 15, l4 = lane >> 4;
  const int bid = blockIdx.x;
  const int g = bid >> 4, qt = bid & 15;
  const int b_ = g / HEADS, h_ = g % HEADS;
  const int qbase = qt * 64 + w * 16;

  bf16x8 qf[2];
  {
    const bf16* qp = Qb + ((size_t)g * NN + qbase + l15) * HD + l4 * 8;
    qf[0] = *(const bf16x8*)qp;
    qf[1] = *(const bf16x8*)(qp + 32);
  }

  f32x4 oacc[4] = {};
  float m_r[4] = {-1e30f, -1e30f, -1e30f, -1e30f};
  float l_r[4] = {};
  const bf16* rpe_h = rpeb + (size_t)h_ * NN * NN;

  const int crow = lane >> 3;
  const int scol = ((lane & 7) * 16) ^ ((crow & 7) << 4); // pre-swizzled source col
  const int cc = w * 2;

#define STAGE(buf, kv0s) do {                                                      \
    _Pragma("unroll")                                                              \
    for (int c2 = 0; c2 < 2; ++c2) {                                               \
      const int c = cc + c2;                                                       \
      const int r = c * 8 + crow;                                                  \
      gload_lds16((const char*)(Kb + ((size_t)g * NN + (kv0s)) * HD) + r * 128 + scol, \
                  (char*)sK[buf] + c * 1024);                                      \
      gload_lds16((const char*)(Vtb + ((size_t)g * HD + r) * NN + (kv0s)) + scol,  \
                  (char*)sV[buf] + c * 1024);                                      \
    } } while (0)

  STAGE(0, 0);
  __syncthreads();
  int cur = 0;

  for (int kv0 = 0; kv0 < NN; kv0 += 64) {
    if (kv0 + 64 < NN) STAGE(cur ^ 1, kv0 + 64);

    // prefetch rpe bias tile into registers (latency hides under MFMAs below)
    float rv[4][4];
#pragma unroll
    for (int nf = 0; nf < 4; ++nf)
#pragma unroll
      for (int rg = 0; rg < 4; ++rg)
        rv[nf][rg] = (float)rpe_h[(size_t)(qbase + l4 * 4 + rg) * NN + kv0 + nf * 16 + l15];

    // S = Q K^T (scale folded into Q)
    f32x4 s[4] = {};
#pragma unroll
    for (int kh = 0; kh < 2; ++kh) {
#pragma unroll
      for (int nf = 0; nf < 4; ++nf) {
        const int n_ = nf * 16 + l15;
        const bf16x8 kf = *(const bf16x8*)((const char*)sK[cur] + n_ * 128 +
                            (((kh * 32 + l4 * 8) * 2) ^ ((n_ & 7) << 4)));
        s[nf] = __builtin_amdgcn_mfma_f32_16x16x32_bf16(qf[kh], kf, s[nf], 0, 0, 0);
      }
    }
    // + rpe bias, row max
    float rm[4] = {-1e30f, -1e30f, -1e30f, -1e30f};
#pragma unroll
    for (int nf = 0; nf < 4; ++nf)
#pragma unroll
      for (int rg = 0; rg < 4; ++rg) {
        float v = s[nf][rg] + rv[nf][rg];
        s[nf][rg] = v;
        rm[rg] = fmaxf(rm[rg], v);
      }
#pragma unroll
    for (int off = 1; off <= 8; off <<= 1)
#pragma unroll
      for (int rg = 0; rg < 4; ++rg)
        rm[rg] = fmaxf(rm[rg], __shfl_xor(rm[rg], off));
    float al[4];
#pragma unroll
    for (int rg = 0; rg < 4; ++rg) {
      const float mn = fmaxf(m_r[rg], rm[rg]);
      al[rg] = __expf(m_r[rg] - mn);
      m_r[rg] = mn;
    }
    float rs[4] = {};
#pragma unroll
    for (int nf = 0; nf < 4; ++nf)
#pragma unroll
      for (int rg = 0; rg < 4; ++rg) {
        const float p = __expf(s[nf][rg] - m_r[rg]);
        rs[rg] += p;
        const int r = l4 * 4 + rg;
        const int cb = (nf * 16 + l15) * 2;
        *(bf16*)((char*)sP + w * 2048 + r * 128 + (cb ^ ((r & 7) << 4))) = (bf16)p;
      }
#pragma unroll
    for (int off = 1; off <= 8; off <<= 1)
#pragma unroll
      for (int rg = 0; rg < 4; ++rg)
        rs[rg] += __shfl_xor(rs[rg], off);
#pragma unroll
    for (int rg = 0; rg < 4; ++rg)
      l_r[rg] = l_r[rg] * al[rg] + rs[rg];
#pragma unroll
    for (int df = 0; df < 4; ++df)
#pragma unroll
      for (int rg = 0; rg < 4; ++rg)
        oacc[df][rg] *= al[rg];

    // O += P V   (sP is per-wave private: no barrier needed, lgkmcnt handles it)
#pragma unroll
    for (int kh = 0; kh < 2; ++kh) {
      const bf16x8 pf = *(const bf16x8*)((const char*)sP + w * 2048 + l15 * 128 +
                          (((kh * 32 + l4 * 8) * 2) ^ ((l15 & 7) << 4)));
#pragma unroll
      for (int df = 0; df < 4; ++df) {
        const int d_ = df * 16 + l15;
        const bf16x8 vf = *(const bf16x8*)((const char*)sV[cur] + d_ * 128 +
                            (((kh * 32 + l4 * 8) * 2) ^ ((d_ & 7) << 4)));
        oacc[df] = __builtin_amdgcn_mfma_f32_16x16x32_bf16(pf, vf, oacc[df], 0, 0, 0);
      }
    }
    __syncthreads();  // drains vmcnt: next tile's staged loads complete; buffer reuse safe
    cur ^= 1;
  }
#undef STAGE

#pragma unroll
  for (int rg = 0; rg < 4; ++rg) {
    const float inv = 1.0f / l_r[rg];
    const int qr = qbase + l4 * 4 + rg;
    bf16* orow = o_attn + ((size_t)(b_ * NN) + qr) * DIM + h_ * HD;
#pragma unroll
    for (int df = 0; df < 4; ++df)
      orow[df * 16 + l15] = (bf16)(oacc[df][rg] * inv);
  }
}

extern "C" void kernel_launch(void* const* d_in, const int* in_sizes, int n_in,
                              void* d_out, int out_size, void* d_ws, size_t ws_size,
                              hipStream_t stream)
{
  const float* x      = (const float*)d_in[0];
  const float* rpe    = (const float*)d_in[1];
  const float* qkv_w  = (const float*)d_in[2];
  const float* proj_w = (const float*)d_in[3];
  const float* proj_b = (const float*)d_in[4];
  const float* ln1_g  = (const float*)d_in[5];
  const float* ln1_b  = (const float*)d_in[6];
  const float* ln2_g  = (const float*)d_in[7];
  const float* ln2_b  = (const float*)d_in[8];
  const float* fc1_w  = (const float*)d_in[9];
  const float* fc1_b  = (const float*)d_in[10];
  const float* fc2_w  = (const float*)d_in[11];
  const float* fc2_b  = (const float*)d_in[12];
  float* out = (float*)d_out;

  char* ws = (char*)d_ws;
  size_t off = 0;
  bf16* qkv_wT  = (bf16*)(ws + off); off += (size_t)2304 * 768 * 2;
  bf16* proj_wT = (bf16*)(ws + off); off += (size_t)768 * 768 * 2;
  bf16* fc1_wT  = (bf16*)(ws + off); off += (size_t)1536 * 768 * 2;
  bf16* fc2_wT  = (bf16*)(ws + off); off += (size_t)768 * 1536 * 2;
  bf16* hbuf    = (bf16*)(ws + off); off += (size_t)ROWS * DIM * 2;   // ln1 out, then o_attn
  bf16* Qb      = (bf16*)(ws + off); off += (size_t)96 * NN * HD * 2; // then h2
  bf16* Kb      = (bf16*)(ws + off); off += (size_t)96 * NN * HD * 2; // then fc1-out (with Vtb)
  bf16* Vtb     = (bf16*)(ws + off); off += (size_t)96 * HD * NN * 2;
  float* x1     = (float*)(ws + off); off += (size_t)ROWS * DIM * 4;
  bf16* o_attn = hbuf;
  bf16* h2 = Qb;
  bf16* hh = Kb;
  bf16* rpeb = (bf16*)x1;   // rpe_bf16 lifetime (prep->attn) disjoint from x1 (proj->end)

  dim3 tb(32, 8);
  wtrans_kernel<<<dim3(2304 / 32, 768 / 32), tb, 0, stream>>>(qkv_w, qkv_wT, 768, 2304);
  wtrans_kernel<<<dim3(768 / 32, 768 / 32),  tb, 0, stream>>>(proj_w, proj_wT, 768, 768);
  wtrans_kernel<<<dim3(1536 / 32, 768 / 32), tb, 0, stream>>>(fc1_w, fc1_wT, 768, 1536);
  wtrans_kernel<<<dim3(768 / 32, 1536 / 32), tb, 0, stream>>>(fc2_w, fc2_wT, 1536, 768);
  rpe_cvt_kernel<<<3072, 256, 0, stream>>>(rpe, rpeb);

  ln_kernel<<<ROWS, 256, 0, stream>>>(x, ln1_g, ln1_b, hbuf);
  gemm128<0><<<dim3(2304 / 128, ROWS / 128), 256, 0, stream>>>(
      hbuf, qkv_wT, ROWS, 2304, 768, nullptr, nullptr, (void*)Qb, (void*)Kb, (void*)Vtb);
  attn_kernel<<<96 * 16, 256, 0, stream>>>(Qb, Kb, Vtb, rpeb, o_attn);
  gemm128<1><<<dim3(768 / 128, ROWS / 128), 256, 0, stream>>>(
      o_attn, proj_wT, ROWS, 768, 768, proj_b, x, (void*)x1, nullptr, nullptr);
  ln_kernel<<<ROWS, 256, 0, stream>>>(x1, ln2_g, ln2_b, h2);
  gemm128<2><<<dim3(1536 / 128, ROWS / 128), 256, 0, stream>>>(
      h2, fc1_wT, ROWS, 1536, 768, fc1_b, nullptr, (void*)hh, nullptr, nullptr);
  gemm128<3><<<dim3(768 / 128, ROWS / 128), 256, 0, stream>>>(
      hh, fc2_wT, ROWS, 768, 1536, fc2_b, x1, (void*)out, nullptr, nullptr);
}